// Round 11
// baseline (72.972 us; speedup 1.0000x reference)
//
#include <hip/hip_runtime.h>

// NQ=8, NL=3, B=65536 — fused single kernel, vectorized-eval edition.
// Grid 256 blocks x 512 thr. Threads (j = t&255, h = t>>8).
// Phase A: thread (j,h) evolves 5 of 9 popcount-class columns (col 4 dup).
// Phase B: restage full row C_j; group h WHTs half of the 81 quadratic
//   products; cross-wave LDS combine writes g[8][92] (group-padded rows).
// Phase C: 128 threads x 2 samples each; coefficients read as ds_read_b128
//   and reused for both samples -> LDS instrs/CU drop ~7x vs R10.

#define ROW 92   // padded coeff row: A@0(9/12) d1@12(16) d2@28(14/16) d3@44(12)
                 // d4@56(10/12) d5@68(8) d6@76(6/8) d7@84(4) d8@88(2/4)

template <int CTRL>
__device__ __forceinline__ float dppf(float x) {
    return __int_as_float(
        __builtin_amdgcn_mov_dpp(__float_as_int(x), CTRL, 0xF, 0xF, true));
}
template <int PAT>
__device__ __forceinline__ float swzp(float x) {
    return __int_as_float(__builtin_amdgcn_ds_swizzle(__float_as_int(x), PAT));
}
template <int B>
__device__ __forceinline__ float lane_xor(float x) {
    if constexpr (B == 0) return dppf<0xB1>(x);        // quad_perm xor1
    else if constexpr (B == 1) return dppf<0x4E>(x);   // quad_perm xor2
    else if constexpr (B == 2) return swzp<0x101F>(x); // ds_swizzle xor4
    else if constexpr (B == 3) return dppf<0x128>(x);  // row_ror:8 == xor8
    else if constexpr (B == 4) return swzp<0x401F>(x); // ds_swizzle xor16
    else return __shfl_xor(x, 32, 64);                 // xor32
}

// Fused RY(wire0) x RY(wire1) on j bits 7,6 — one LDS round, 5 columns.
__device__ __forceinline__ void gate_lds2_5(float2 Cv[5], float2 (*xch)[256],
                                            float2 cs0, float2 cs1,
                                            int j, int M0) {
    __syncthreads();
    #pragma unroll
    for (int m = 0; m < 5; ++m) xch[M0 + m][j] = Cv[m];
    __syncthreads();
    const float s0 = (j & 128) ? cs0.y : -cs0.y;
    const float s1 = (j & 64)  ? cs1.y : -cs1.y;
    const float a00 = cs0.x * cs1.x, a01 = cs0.x * s1;
    const float a10 = s0 * cs1.x,    a11 = s0 * s1;
    #pragma unroll
    for (int m = 0; m < 5; ++m) {
        const float2 p01 = xch[M0 + m][j ^ 64];
        const float2 p10 = xch[M0 + m][j ^ 128];
        const float2 p11 = xch[M0 + m][j ^ 192];
        Cv[m].x = a00 * Cv[m].x + a01 * p01.x + a10 * p10.x + a11 * p11.x;
        Cv[m].y = a00 * Cv[m].y + a01 * p01.y + a10 * p10.y + a11 * p11.y;
    }
}

template <int B>
__device__ __forceinline__ void gate_wave5(float2 Cv[5], float2 cs, int j) {
    const float sg = ((j >> B) & 1) ? cs.y : -cs.y;
    #pragma unroll
    for (int m = 0; m < 5; ++m) {
        const float pr = lane_xor<B>(Cv[m].x);
        const float pi = lane_xor<B>(Cv[m].y);
        Cv[m].x = cs.x * Cv[m].x + sg * pr;
        Cv[m].y = cs.x * Cv[m].y + sg * pi;
    }
}

template <int N>
__device__ __forceinline__ void wht_chunk(float (&v)[N], float* buf,
                                          int lane, int wvg, int row, int base) {
    #define WHT_LVL(B)                                                   \
    {                                                                    \
        const float sgn = ((lane >> (B)) & 1) ? -1.f : 1.f;              \
        _Pragma("unroll")                                                \
        for (int i = 0; i < N; ++i) {                                    \
            const float p = lane_xor<B>(v[i]);                           \
            v[i] = fmaf(sgn, v[i], p);                                   \
        }                                                                \
    }
    WHT_LVL(0) WHT_LVL(1) WHT_LVL(2) WHT_LVL(3) WHT_LVL(4) WHT_LVL(5)
    #undef WHT_LVL
    if (row >= 0) {
        #pragma unroll
        for (int i = 0; i < N; ++i) buf[(wvg * 7 + row) * 81 + base + i] = v[i];
    }
}

template <int D, int N>
__device__ __forceinline__ void fill_pairs(const float2 (&C9)[9], float (&c)[N],
                                           int off) {
    #pragma unroll
    for (int k = 0; k + D <= 8; ++k) {
        const float2 hi = C9[k + D], lo = C9[k];
        c[off + 2 * k]     = 2.f * (hi.x * lo.x + hi.y * lo.y);
        c[off + 2 * k + 1] = 2.f * (hi.y * lo.x - hi.x * lo.y);
    }
}

// ---- phase C helpers (all static-index; coefficients shared by 2 samples)
__device__ __forceinline__ void prep(float z1v, float z2v, float& u, float& w8,
                                     float Tr[9], float Ti[9]) {
    const float u1 = sqrtf(fmaxf(0.f, 1.f - z1v * z1v));   // cos a1
    const float q1 = 0.5f * (1.f + u1);                     // cos^2(a1/2)
    const float s1 = copysignf(sqrtf(fmaxf(0.f, 0.5f * (1.f - u1))), z1v);
    const float tn = s1 * rsqrtf(q1);                       // tan(a1/2)
    const float u2 = sqrtf(fmaxf(0.f, 1.f - z2v * z2v));    // cos a2
    const float tr = tn * u2, ti = tn * z2v;                // t = tn e^{i a2}
    u = tn * tn;
    w8 = q1 * q1; w8 *= w8; w8 *= w8;                       // q1^8
    Tr[1] = tr; Ti[1] = ti;
    #pragma unroll
    for (int d = 2; d <= 8; ++d) {
        Tr[d] = Tr[d - 1] * tr - Ti[d - 1] * ti;
        Ti[d] = Tr[d - 1] * ti + Ti[d - 1] * tr;
    }
}

__device__ __forceinline__ void apoly2(const float* gp, float u0, float u1,
                                       float& r0, float& r1) {
    const float4 c0 = ((const float4*)gp)[0];
    const float4 c1 = ((const float4*)gp)[1];
    const float4 c2 = ((const float4*)gp)[2];
    const float a[9] = {c0.x, c0.y, c0.z, c0.w, c1.x, c1.y, c1.z, c1.w, c2.x};
    r0 = a[8]; r1 = a[8];
    #pragma unroll
    for (int m = 7; m >= 0; --m) {
        r0 = fmaf(r0, u0, a[m]);
        r1 = fmaf(r1, u1, a[m]);
    }
}

template <int NP>   // NP = number of (re,im) pairs, ascending k
__device__ __forceinline__ void bpoly2(const float* gp, float u0, float u1,
                                       float2& b0, float2& b1) {
    constexpr int NF4 = (2 * NP + 3) / 4;
    float4 c[NF4];
    const float4* p = (const float4*)gp;
    #pragma unroll
    for (int i = 0; i < NF4; ++i) c[i] = p[i];
    float br0 = 0.f, bi0 = 0.f, br1 = 0.f, bi1 = 0.f;
    #pragma unroll
    for (int k = NP - 1; k >= 0; --k) {           // static indices only
        const float re = (k & 1) ? c[k >> 1].z : c[k >> 1].x;
        const float im = (k & 1) ? c[k >> 1].w : c[k >> 1].y;
        br0 = fmaf(br0, u0, re); bi0 = fmaf(bi0, u0, im);
        br1 = fmaf(br1, u1, re); bi1 = fmaf(bi1, u1, im);
    }
    b0 = make_float2(br0, bi0);
    b1 = make_float2(br1, bi1);
}

__global__ __launch_bounds__(512, 1)
void qsim_fused(const float* __restrict__ w, const float* __restrict__ z1,
                const float* __restrict__ z2, float* __restrict__ out,
                int nsamp) {
    __shared__ float2 xch[9][256];              // 18 KB gate/WHT buffer
    __shared__ float2 s_cs[3][8];
    __shared__ __align__(16) float g[8 * ROW];  // padded coeff rows

    const int t = threadIdx.x;
    const int j = t & 255;
    const int h = t >> 8;
    const int M0 = h * 4;
    const int lane = t & 63, wvg = (t >> 6) & 3;

    // ---- phase C prep hoisted (2 samples per eval thread, t < 128)
    const int s0 = blockIdx.x * 256 + t;
    const int s1 = s0 + 128;
    const bool e0 = (t < 128) && (s0 < nsamp);
    const bool e1 = (t < 128) && (s1 < nsamp);
    float u0 = 0.f, u1 = 0.f, w80 = 0.f, w81 = 0.f;
    float Tr0[9], Ti0[9], Tr1[9], Ti1[9];
    if (e0) prep(z1[s0], z2[s0], u0, w80, Tr0, Ti0);
    if (e1) prep(z1[s1], z2[s1], u1, w81, Tr1, Ti1);

    if (t < 24) {
        int l = t >> 3, q = t & 7;
        float a = 0.5f * w[l * 15 + q];
        s_cs[l][q] = make_float2(__cosf(a), __sinf(a));
    }
    __syncthreads();

    // ---- phase A: evolve 5 owned columns; pair (j,0/1) covers all 9
    float2 Cv[5];
    #pragma unroll
    for (int m = 0; m < 5; ++m)
        Cv[m] = make_float2((__popc(j) == M0 + m) ? 1.f : 0.f, 0.f);

    for (int l = 0; l < 3; ++l) {
        gate_lds2_5(Cv, xch, s_cs[l][0], s_cs[l][1], j, M0);  // bits 7,6
        gate_wave5<5>(Cv, s_cs[l][2], j);
        gate_wave5<4>(Cv, s_cs[l][3], j);
        gate_wave5<3>(Cv, s_cs[l][4], j);
        gate_wave5<2>(Cv, s_cs[l][5], j);
        gate_wave5<1>(Cv, s_cs[l][6], j);
        gate_wave5<0>(Cv, s_cs[l][7], j);
        if (l < 2) {                              // RZZ diag (last one cancels)
            float ang = 0.f;
            #pragma unroll
            for (int i = 0; i < 7; ++i) {
                float zz = (((j >> (7 - i)) ^ (j >> (6 - i))) & 1) ? -1.f : 1.f;
                ang = fmaf(w[l * 15 + 8 + i], zz, ang);
            }
            float s2, c2;
            __sincosf(0.5f * ang, &s2, &c2);
            #pragma unroll
            for (int m = 0; m < 5; ++m) {
                const float nr = Cv[m].x * c2 + Cv[m].y * s2;
                const float ni = Cv[m].y * c2 - Cv[m].x * s2;
                Cv[m].x = nr; Cv[m].y = ni;
            }
        }
    }

    // ---- restage: every thread gets the full row C_j
    __syncthreads();
    #pragma unroll
    for (int m = 0; m < 5; ++m) xch[M0 + m][j] = Cv[m];
    __syncthreads();
    float2 C9[9];
    #pragma unroll
    for (int m = 0; m < 9; ++m) C9[m] = xch[m][j];
    __syncthreads();

    // ---- phase B: group h WHTs its component subset
    float* buf = (float*)xch + h * (28 * 81);
    const int row = (lane == 0) ? 0 : (lane == 1) ? 1 : (lane == 2) ? 2 :
                    (lane == 4) ? 3 : (lane == 8) ? 4 : (lane == 16) ? 5 :
                    (lane == 32) ? 6 : -1;
    if (h == 0) {                    // components 0..38: diag, d=1, d=2
        {   float c[9];
            #pragma unroll
            for (int m = 0; m < 9; ++m)
                c[m] = C9[m].x * C9[m].x + C9[m].y * C9[m].y;
            wht_chunk(c, buf, lane, wvg, row, 0);
        }
        { float c[16]; fill_pairs<1>(C9, c, 0); wht_chunk(c, buf, lane, wvg, row, 9);  }
        { float c[14]; fill_pairs<2>(C9, c, 0); wht_chunk(c, buf, lane, wvg, row, 25); }
    } else {                         // components 39..80: d=3..8
        { float c[12]; fill_pairs<3>(C9, c, 0); wht_chunk(c, buf, lane, wvg, row, 39); }
        { float c[10]; fill_pairs<4>(C9, c, 0); wht_chunk(c, buf, lane, wvg, row, 51); }
        { float c[8];  fill_pairs<5>(C9, c, 0); wht_chunk(c, buf, lane, wvg, row, 61); }
        {   float c[12];
            fill_pairs<6>(C9, c, 0);
            fill_pairs<7>(C9, c, 6);
            fill_pairs<8>(C9, c, 10);
            wht_chunk(c, buf, lane, wvg, row, 69);
        }
    }
    __syncthreads();
    // cross-wave combine into padded rows; qubit q <-> idx bit b = 7-q
    for (int o = t; o < 648; o += 512) {
        const int q = o / 81, i = o - 81 * q;
        const int b = 7 - q;
        const float* gb = (const float*)xch + ((i < 39) ? 0 : 28 * 81);
        float r;
        if (b < 6) {
            const int rw = b + 1;
            r = gb[(0 * 7 + rw) * 81 + i] + gb[(1 * 7 + rw) * 81 + i] +
                gb[(2 * 7 + rw) * 81 + i] + gb[(3 * 7 + rw) * 81 + i];
        } else if (b == 6) {
            r = gb[(0 * 7) * 81 + i] - gb[(1 * 7) * 81 + i] +
                gb[(2 * 7) * 81 + i] - gb[(3 * 7) * 81 + i];
        } else {
            r = gb[(0 * 7) * 81 + i] + gb[(1 * 7) * 81 + i] -
                gb[(2 * 7) * 81 + i] - gb[(3 * 7) * 81 + i];
        }
        // compact index -> padded offset (group-aligned float4 rows)
        const int off = i + ((i < 9) ? 0 : (i < 39) ? 3 : (i < 61) ? 5 :
                             (i < 75) ? 7 : 9);
        g[q * ROW + off] = r;
    }
    __syncthreads();

    // ---- phase C: 128 threads, 2 samples each, b128 coefficient reads
    if (!e0) return;

    float o0[8], o1[8];
    #pragma unroll
    for (int q = 0; q < 8; ++q) {
        const float* gq = g + q * ROW;
        float r0, r1;
        apoly2(gq, u0, u1, r0, r1);
        #define DTERM(D, NP, OFF)                                        \
        {                                                                \
            float2 b0, b1;                                               \
            bpoly2<NP>(gq + OFF, u0, u1, b0, b1);                        \
            r0 = fmaf(Tr0[D], b0.x, r0); r0 = fmaf(-Ti0[D], b0.y, r0);   \
            r1 = fmaf(Tr1[D], b1.x, r1); r1 = fmaf(-Ti1[D], b1.y, r1);   \
        }
        DTERM(1, 8, 12) DTERM(2, 7, 28) DTERM(3, 6, 44) DTERM(4, 5, 56)
        DTERM(5, 4, 68) DTERM(6, 3, 76) DTERM(7, 2, 84) DTERM(8, 1, 88)
        #undef DTERM
        o0[q] = w80 * r0;
        o1[q] = w81 * r1;
    }

    {
        float4* op = (float4*)(out + (size_t)s0 * 8);
        op[0] = make_float4(o0[0], o0[1], o0[2], o0[3]);
        op[1] = make_float4(o0[4], o0[5], o0[6], o0[7]);
    }
    if (e1) {
        float4* op = (float4*)(out + (size_t)s1 * 8);
        op[0] = make_float4(o1[0], o1[1], o1[2], o1[3]);
        op[1] = make_float4(o1[4], o1[5], o1[6], o1[7]);
    }
}

extern "C" void kernel_launch(void* const* d_in, const int* in_sizes, int n_in,
                              void* d_out, int out_size, void* d_ws,
                              size_t ws_size, hipStream_t stream) {
    const float* w  = (const float*)d_in[0];   // (3, 15) f32
    const float* z1 = (const float*)d_in[1];   // (B,)   f32
    const float* z2 = (const float*)d_in[2];   // (B,)   f32
    float* out = (float*)d_out;                // (B, 8) f32

    const int n = in_sizes[1];
    qsim_fused<<<(n + 255) / 256, 512, 0, stream>>>(w, z1, z2, out, n);
}

// Round 12
// 16.299 us; speedup vs baseline: 4.4771x; 4.4771x over previous
//
#include <hip/hip_runtime.h>

// NQ=8, NL=3, B=65536 — fused single kernel. R10 structure + b128 eval.
// Grid 256 blocks x 512 thr. Threads (j = t&255, h = t>>8).
// Phase A: thread (j,h) evolves 5 of 9 popcount-class columns (col 4 dup).
// Phase B: restage full row C_j; group h WHTs half of the 81 quadratic
//   products; cross-wave combine writes PADDED rows g[8][92] (16B groups).
// Phase C: all 512 threads: thread (j,h) evaluates sample j of this block,
//   qubits [4h,4h+4), coefficients via ds_read_b128 (92/thread vs R10's 324
//   scalar reads for 8 qubits) -> phase-C LDS pipe time ~6.3 -> ~3.7 us.
// Per-thread live state kept at R10 levels (R11's 2-sample variant spilled).

#define ROW 92   // padded coeff row: A@0(9) d1@12(16) d2@28(14) d3@44(12)
                 // d4@56(10) d5@68(8) d6@76(6) d7@84(4) d8@88(2)

template <int CTRL>
__device__ __forceinline__ float dppf(float x) {
    return __int_as_float(
        __builtin_amdgcn_mov_dpp(__float_as_int(x), CTRL, 0xF, 0xF, true));
}
template <int PAT>
__device__ __forceinline__ float swzp(float x) {
    return __int_as_float(__builtin_amdgcn_ds_swizzle(__float_as_int(x), PAT));
}
template <int B>
__device__ __forceinline__ float lane_xor(float x) {
    if constexpr (B == 0) return dppf<0xB1>(x);        // quad_perm xor1
    else if constexpr (B == 1) return dppf<0x4E>(x);   // quad_perm xor2
    else if constexpr (B == 2) return swzp<0x101F>(x); // ds_swizzle xor4
    else if constexpr (B == 3) return dppf<0x128>(x);  // row_ror:8 == xor8
    else if constexpr (B == 4) return swzp<0x401F>(x); // ds_swizzle xor16
    else return __shfl_xor(x, 32, 64);                 // xor32
}

// Fused RY(wire0) x RY(wire1) on j bits 7,6 — one LDS round, 5 columns.
__device__ __forceinline__ void gate_lds2_5(float2 Cv[5], float2 (*xch)[256],
                                            float2 cs0, float2 cs1,
                                            int j, int M0) {
    __syncthreads();
    #pragma unroll
    for (int m = 0; m < 5; ++m) xch[M0 + m][j] = Cv[m];
    __syncthreads();
    const float s0 = (j & 128) ? cs0.y : -cs0.y;
    const float s1 = (j & 64)  ? cs1.y : -cs1.y;
    const float a00 = cs0.x * cs1.x, a01 = cs0.x * s1;
    const float a10 = s0 * cs1.x,    a11 = s0 * s1;
    #pragma unroll
    for (int m = 0; m < 5; ++m) {
        const float2 p01 = xch[M0 + m][j ^ 64];
        const float2 p10 = xch[M0 + m][j ^ 128];
        const float2 p11 = xch[M0 + m][j ^ 192];
        Cv[m].x = a00 * Cv[m].x + a01 * p01.x + a10 * p10.x + a11 * p11.x;
        Cv[m].y = a00 * Cv[m].y + a01 * p01.y + a10 * p10.y + a11 * p11.y;
    }
}

template <int B>
__device__ __forceinline__ void gate_wave5(float2 Cv[5], float2 cs, int j) {
    const float sg = ((j >> B) & 1) ? cs.y : -cs.y;
    #pragma unroll
    for (int m = 0; m < 5; ++m) {
        const float pr = lane_xor<B>(Cv[m].x);
        const float pi = lane_xor<B>(Cv[m].y);
        Cv[m].x = cs.x * Cv[m].x + sg * pr;
        Cv[m].y = cs.x * Cv[m].y + sg * pi;
    }
}

template <int N>
__device__ __forceinline__ void wht_chunk(float (&v)[N], float* buf,
                                          int lane, int wvg, int row, int base) {
    #define WHT_LVL(B)                                                   \
    {                                                                    \
        const float sgn = ((lane >> (B)) & 1) ? -1.f : 1.f;              \
        _Pragma("unroll")                                                \
        for (int i = 0; i < N; ++i) {                                    \
            const float p = lane_xor<B>(v[i]);                           \
            v[i] = fmaf(sgn, v[i], p);                                   \
        }                                                                \
    }
    WHT_LVL(0) WHT_LVL(1) WHT_LVL(2) WHT_LVL(3) WHT_LVL(4) WHT_LVL(5)
    #undef WHT_LVL
    if (row >= 0) {
        #pragma unroll
        for (int i = 0; i < N; ++i) buf[(wvg * 7 + row) * 81 + base + i] = v[i];
    }
}

template <int D, int N>
__device__ __forceinline__ void fill_pairs(const float2 (&C9)[9], float (&c)[N],
                                           int off) {
    #pragma unroll
    for (int k = 0; k + D <= 8; ++k) {
        const float2 hi = C9[k + D], lo = C9[k];
        c[off + 2 * k]     = 2.f * (hi.x * lo.x + hi.y * lo.y);
        c[off + 2 * k + 1] = 2.f * (hi.y * lo.x - hi.x * lo.y);
    }
}

// ---- phase C helpers (single sample, static indices)
__device__ __forceinline__ void prep(float z1v, float z2v, float& u, float& w8,
                                     float Tr[9], float Ti[9]) {
    const float u1 = sqrtf(fmaxf(0.f, 1.f - z1v * z1v));   // cos a1
    const float q1 = 0.5f * (1.f + u1);                     // cos^2(a1/2)
    const float s1 = copysignf(sqrtf(fmaxf(0.f, 0.5f * (1.f - u1))), z1v);
    const float tn = s1 * rsqrtf(q1);                       // tan(a1/2)
    const float u2 = sqrtf(fmaxf(0.f, 1.f - z2v * z2v));    // cos a2
    const float tr = tn * u2, ti = tn * z2v;                // t = tn e^{i a2}
    u = tn * tn;
    w8 = q1 * q1; w8 *= w8; w8 *= w8;                       // q1^8
    Tr[1] = tr; Ti[1] = ti;
    #pragma unroll
    for (int d = 2; d <= 8; ++d) {
        Tr[d] = Tr[d - 1] * tr - Ti[d - 1] * ti;
        Ti[d] = Tr[d - 1] * ti + Ti[d - 1] * tr;
    }
}

__device__ __forceinline__ float apoly1(const float* gp, float u) {
    const float4 c0 = ((const float4*)gp)[0];
    const float4 c1 = ((const float4*)gp)[1];
    const float4 c2 = ((const float4*)gp)[2];
    const float a[9] = {c0.x, c0.y, c0.z, c0.w, c1.x, c1.y, c1.z, c1.w, c2.x};
    float r = a[8];
    #pragma unroll
    for (int m = 7; m >= 0; --m) r = fmaf(r, u, a[m]);
    return r;
}

template <int NP>   // NP (re,im) pairs, ascending k; returns (br, bi)
__device__ __forceinline__ float2 bpoly1(const float* gp, float u) {
    constexpr int NF4 = (2 * NP + 3) / 4;
    float4 c[NF4];
    const float4* p = (const float4*)gp;
    #pragma unroll
    for (int i = 0; i < NF4; ++i) c[i] = p[i];
    float br = 0.f, bi = 0.f;
    #pragma unroll
    for (int k = NP - 1; k >= 0; --k) {           // static indices only
        const float re = (k & 1) ? c[k >> 1].z : c[k >> 1].x;
        const float im = (k & 1) ? c[k >> 1].w : c[k >> 1].y;
        br = fmaf(br, u, re);
        bi = fmaf(bi, u, im);
    }
    return make_float2(br, bi);
}

__global__ __launch_bounds__(512, 2)
void qsim_fused(const float* __restrict__ w, const float* __restrict__ z1,
                const float* __restrict__ z2, float* __restrict__ out,
                int nsamp) {
    __shared__ float2 xch[9][256];              // 18 KB gate/WHT buffer
    __shared__ float2 s_cs[3][8];
    __shared__ __align__(16) float g[8 * ROW];  // padded coeff rows

    const int t = threadIdx.x;
    const int j = t & 255;           // basis index AND sample slot
    const int h = t >> 8;            // column group / qubit-half
    const int M0 = h * 4;
    const int lane = t & 63, wvg = (t >> 6) & 3;

    // ---- phase C prep hoisted: z-load latency hides under phase A
    const int s = blockIdx.x * 256 + j;
    const bool ev = (s < nsamp);
    float u = 0.f, w8 = 0.f;
    float Tr[9], Ti[9];
    if (ev) prep(z1[s], z2[s], u, w8, Tr, Ti);

    if (t < 24) {
        int l = t >> 3, q = t & 7;
        float a = 0.5f * w[l * 15 + q];
        s_cs[l][q] = make_float2(__cosf(a), __sinf(a));
    }
    __syncthreads();

    // ---- phase A: evolve 5 owned columns; pair (j,0/1) covers all 9
    float2 Cv[5];
    #pragma unroll
    for (int m = 0; m < 5; ++m)
        Cv[m] = make_float2((__popc(j) == M0 + m) ? 1.f : 0.f, 0.f);

    for (int l = 0; l < 3; ++l) {
        gate_lds2_5(Cv, xch, s_cs[l][0], s_cs[l][1], j, M0);  // bits 7,6
        gate_wave5<5>(Cv, s_cs[l][2], j);
        gate_wave5<4>(Cv, s_cs[l][3], j);
        gate_wave5<3>(Cv, s_cs[l][4], j);
        gate_wave5<2>(Cv, s_cs[l][5], j);
        gate_wave5<1>(Cv, s_cs[l][6], j);
        gate_wave5<0>(Cv, s_cs[l][7], j);
        if (l < 2) {                              // RZZ diag (last one cancels)
            float ang = 0.f;
            #pragma unroll
            for (int i = 0; i < 7; ++i) {
                float zz = (((j >> (7 - i)) ^ (j >> (6 - i))) & 1) ? -1.f : 1.f;
                ang = fmaf(w[l * 15 + 8 + i], zz, ang);
            }
            float s2, c2;
            __sincosf(0.5f * ang, &s2, &c2);
            #pragma unroll
            for (int m = 0; m < 5; ++m) {
                const float nr = Cv[m].x * c2 + Cv[m].y * s2;
                const float ni = Cv[m].y * c2 - Cv[m].x * s2;
                Cv[m].x = nr; Cv[m].y = ni;
            }
        }
    }

    // ---- restage: every thread gets the full row C_j
    __syncthreads();
    #pragma unroll
    for (int m = 0; m < 5; ++m) xch[M0 + m][j] = Cv[m];
    __syncthreads();
    float2 C9[9];
    #pragma unroll
    for (int m = 0; m < 9; ++m) C9[m] = xch[m][j];
    __syncthreads();

    // ---- phase B: group h WHTs its component subset
    float* buf = (float*)xch + h * (28 * 81);
    const int row = (lane == 0) ? 0 : (lane == 1) ? 1 : (lane == 2) ? 2 :
                    (lane == 4) ? 3 : (lane == 8) ? 4 : (lane == 16) ? 5 :
                    (lane == 32) ? 6 : -1;
    if (h == 0) {                    // components 0..38: diag, d=1, d=2
        {   float c[9];
            #pragma unroll
            for (int m = 0; m < 9; ++m)
                c[m] = C9[m].x * C9[m].x + C9[m].y * C9[m].y;
            wht_chunk(c, buf, lane, wvg, row, 0);
        }
        { float c[16]; fill_pairs<1>(C9, c, 0); wht_chunk(c, buf, lane, wvg, row, 9);  }
        { float c[14]; fill_pairs<2>(C9, c, 0); wht_chunk(c, buf, lane, wvg, row, 25); }
    } else {                         // components 39..80: d=3..8
        { float c[12]; fill_pairs<3>(C9, c, 0); wht_chunk(c, buf, lane, wvg, row, 39); }
        { float c[10]; fill_pairs<4>(C9, c, 0); wht_chunk(c, buf, lane, wvg, row, 51); }
        { float c[8];  fill_pairs<5>(C9, c, 0); wht_chunk(c, buf, lane, wvg, row, 61); }
        {   float c[12];
            fill_pairs<6>(C9, c, 0);
            fill_pairs<7>(C9, c, 6);
            fill_pairs<8>(C9, c, 10);
            wht_chunk(c, buf, lane, wvg, row, 69);
        }
    }
    __syncthreads();
    // cross-wave combine into padded rows; qubit q <-> idx bit b = 7-q
    for (int o = t; o < 648; o += 512) {
        const int q = o / 81, i = o - 81 * q;
        const int b = 7 - q;
        const float* gb = (const float*)xch + ((i < 39) ? 0 : 28 * 81);
        float r;
        if (b < 6) {
            const int rw = b + 1;
            r = gb[(0 * 7 + rw) * 81 + i] + gb[(1 * 7 + rw) * 81 + i] +
                gb[(2 * 7 + rw) * 81 + i] + gb[(3 * 7 + rw) * 81 + i];
        } else if (b == 6) {
            r = gb[(0 * 7) * 81 + i] - gb[(1 * 7) * 81 + i] +
                gb[(2 * 7) * 81 + i] - gb[(3 * 7) * 81 + i];
        } else {
            r = gb[(0 * 7) * 81 + i] + gb[(1 * 7) * 81 + i] -
                gb[(2 * 7) * 81 + i] - gb[(3 * 7) * 81 + i];
        }
        // compact index -> padded offset (16B-aligned d-groups)
        const int off = i + ((i < 9) ? 0 : (i < 39) ? 3 : (i < 61) ? 5 :
                             (i < 75) ? 7 : 9);
        g[q * ROW + off] = r;
    }
    __syncthreads();

    // ---- phase C: thread (j,h) evaluates sample s, qubits [4h, 4h+4)
    if (!ev) return;

    float o4[4];
    #pragma unroll
    for (int qq = 0; qq < 4; ++qq) {
        const float* gq = g + (M0 + qq) * ROW;
        float r = apoly1(gq, u);
        #define DTERM(D, NP, OFF)                                        \
        {                                                                \
            const float2 b = bpoly1<NP>(gq + OFF, u);                    \
            r = fmaf(Tr[D], b.x, r);                                     \
            r = fmaf(-Ti[D], b.y, r);                                    \
        }
        DTERM(1, 8, 12) DTERM(2, 7, 28) DTERM(3, 6, 44) DTERM(4, 5, 56)
        DTERM(5, 4, 68) DTERM(6, 3, 76) DTERM(7, 2, 84) DTERM(8, 1, 88)
        #undef DTERM
        o4[qq] = w8 * r;
    }

    float4* op = (float4*)(out + (size_t)s * 8 + M0);
    *op = make_float4(o4[0], o4[1], o4[2], o4[3]);
}

extern "C" void kernel_launch(void* const* d_in, const int* in_sizes, int n_in,
                              void* d_out, int out_size, void* d_ws,
                              size_t ws_size, hipStream_t stream) {
    const float* w  = (const float*)d_in[0];   // (3, 15) f32
    const float* z1 = (const float*)d_in[1];   // (B,)   f32
    const float* z2 = (const float*)d_in[2];   // (B,)   f32
    float* out = (float*)d_out;                // (B, 8) f32

    const int n = in_sizes[1];
    qsim_fused<<<(n + 255) / 256, 512, 0, stream>>>(w, z1, z2, out, n);
}